// Round 1
// baseline (159.491 us; speedup 1.0000x reference)
//
#include <hip/hip_runtime.h>

// MedSegNet texture features: 3x3 zero-padded window per (b,c,h,w):
//  contrast, energy, entropy, homogeneity -> martingale transform.
// theta=1 => M = clamp(max(f,1e-5)*exp(-0.5), 1e-4, 1e4); all feats <= 1 so
// the EXP_MAX clamp / isfinite path is dead code (see analysis).

#define Wd 128
#define Hd 128
#define HWd 16384

__device__ __forceinline__ float mart(float f) {
    float fc = fmaxf(f, 1e-5f);
    float M = fc * 0.60653065971263342f;   // exp(-0.5)
    return fminf(fmaxf(M, 1e-4f), 1e4f);
}

__global__ __launch_bounds__(256) void medseg_kernel(const float* __restrict__ x,
                                                     float* __restrict__ out,
                                                     int n_planes) {
    int tid = blockIdx.x * 256 + threadIdx.x;
    int plane = tid >> 12;                // 4096 threads per 128x128 plane
    if (plane >= n_planes) return;
    int rem = tid & 4095;
    int h = rem >> 5;                     // 32 groups-of-4 per row
    int w0 = (rem & 31) << 2;

    const float* xp = x + (size_t)plane * HWd;

    // 3 rows x 6 cols window (cols w0-1 .. w0+4), zero-padded
    float r[3][6];
#pragma unroll
    for (int dr = 0; dr < 3; ++dr) {
        int hh = h + dr - 1;
        if (hh < 0 || hh >= Hd) {
#pragma unroll
            for (int j = 0; j < 6; ++j) r[dr][j] = 0.f;
        } else {
            const float* row = xp + hh * Wd;
            float4 v = *reinterpret_cast<const float4*>(row + w0);
            r[dr][0] = (w0 > 0) ? row[w0 - 1] : 0.f;
            r[dr][1] = v.x; r[dr][2] = v.y; r[dr][3] = v.z; r[dr][4] = v.w;
            r[dr][5] = (w0 + 4 < Wd) ? row[w0 + 4] : 0.f;
        }
    }

    // column partial sums shared across the 4 output pixels
    float colS[6], colE[6], colN[6];
#pragma unroll
    for (int j = 0; j < 6; ++j) {
        float s = 0.f, e = 0.f, en = 0.f;
#pragma unroll
        for (int dr = 0; dr < 3; ++dr) {
            float v = r[dr][j];
            s += v;
            e = fmaf(v, v, e);
            float cl = fmaxf(v, 1e-6f);
            en = fmaf(cl, __logf(cl), en);
        }
        colS[j] = s; colE[j] = e; colN[j] = en;
    }

    float con[4], ene[4], ent[4], hom[4];
#pragma unroll
    for (int i = 0; i < 4; ++i) {
        float sum = colS[i] + colS[i + 1] + colS[i + 2];
        float m = sum * (1.f / 9.f);
        float energy = (colE[i] + colE[i + 1] + colE[i + 2]) * (1.f / 9.f);
        float entropy = -(colN[i] + colN[i + 1] + colN[i + 2]) * (1.f / 9.f);

        float s2 = 0.f, sa = 0.f;
#pragma unroll
        for (int dr = 0; dr < 3; ++dr) {
#pragma unroll
            for (int dj = 0; dj < 3; ++dj) {
                float c = r[dr][i + dj] - m;
                s2 = fmaf(c, c, s2);
                sa += fabsf(c);
            }
        }
        float var = s2 * 0.125f;                      // ddof=1 -> /8
        float sd = fmaxf(sqrtf(var), 1e-3f);
        float contrast = s2 * (1.f / 9.f) / (sd * sd);
        float homog = 1.f / ((9.f + sa) * (1.f / 9.f) + 1e-6f);

        con[i] = mart(contrast);
        ene[i] = mart(energy);
        ent[i] = mart(entropy);
        hom[i] = mart(homog);
    }

    size_t base = (size_t)plane * 4 * HWd + h * Wd + w0;
    *reinterpret_cast<float4*>(out + base)           = make_float4(con[0], con[1], con[2], con[3]);
    *reinterpret_cast<float4*>(out + base + HWd)     = make_float4(ene[0], ene[1], ene[2], ene[3]);
    *reinterpret_cast<float4*>(out + base + 2 * HWd) = make_float4(ent[0], ent[1], ent[2], ent[3]);
    *reinterpret_cast<float4*>(out + base + 3 * HWd) = make_float4(hom[0], hom[1], hom[2], hom[3]);
}

extern "C" void kernel_launch(void* const* d_in, const int* in_sizes, int n_in,
                              void* d_out, int out_size, void* d_ws, size_t ws_size,
                              hipStream_t stream) {
    const float* x = (const float*)d_in[0];
    float* out = (float*)d_out;
    int n_planes = in_sizes[0] / HWd;            // B*C = 512
    int total_threads = n_planes * (HWd / 4);
    int blocks = (total_threads + 255) / 256;
    medseg_kernel<<<blocks, 256, 0, stream>>>(x, out, n_planes);
}